// Round 7
// baseline (486.818 us; speedup 1.0000x reference)
//
#include <hip/hip_runtime.h>
#include <math.h>

#define TOPK 32
#define NVAL 32768
#define D 4096

typedef __attribute__((ext_vector_type(8))) short bf16x8;
typedef __attribute__((ext_vector_type(4))) float f32x4;

__device__ inline short f2bf(float x) {
    union { float f; unsigned u; } v; v.f = x;
    unsigned r = v.u + 0x7fffu + ((v.u >> 16) & 1u);  // RNE
    return (short)(r >> 16);
}
__device__ inline float bf2f(short h) {
    union { unsigned u; float f; } v; v.u = ((unsigned)(unsigned short)h) << 16;
    return v.f;
}

// ---------------- fp32 -> bf16 hi/lo split convert ----------------
__global__ __launch_bounds__(256) void cvt_split_kernel(
    const float* __restrict__ in, short* __restrict__ hi, short* __restrict__ lo, int n4)
{
    int i = blockIdx.x * 256 + threadIdx.x;
    if (i < n4) {
        float4 v = ((const float4*)in)[i];
        short4 h = {f2bf(v.x), f2bf(v.y), f2bf(v.z), f2bf(v.w)};
        short4 l = {f2bf(v.x - bf2f(h.x)), f2bf(v.y - bf2f(h.y)),
                    f2bf(v.z - bf2f(h.z)), f2bf(v.w - bf2f(h.w))};
        ((short4*)hi)[i] = h;
        ((short4*)lo)[i] = l;
    }
}

// ------- exact-ish GEMM via split-bf16 (hi/lo, 3 MFMA): err sigma ~5e-6 rel scale -------
// C[+part] [128 x N] = A(hi+lo)[128 x K] @ (hi+lo of B[N x K])^T ; grid.y = K-split.
__global__ __launch_bounds__(256) void gemm_split_kernel(
    const short* __restrict__ Ahi, const short* __restrict__ Alo,
    const float* __restrict__ B, float* __restrict__ C, int K, int N, int klen)
{
    const int t = threadIdx.x;
    const int lane = t & 63;
    const int w = t >> 6;
    const int ntile = blockIdx.x * 64 + w * 16;
    const int k0 = blockIdx.y * klen;
    float* Cb = C + (size_t)blockIdx.y * 128 * N;

    const int kfrag = (lane >> 4) * 8;
    const float* bp = B + (size_t)(ntile + (lane & 15)) * K + kfrag;
    const short* aph = Ahi + (size_t)(lane & 15) * K + kfrag;
    const short* apl = Alo + (size_t)(lane & 15) * K + kfrag;

    f32x4 acc[8];
    #pragma unroll
    for (int j = 0; j < 8; ++j) acc[j] = (f32x4){0.f, 0.f, 0.f, 0.f};

    float4 x0 = *(const float4*)(bp + k0);
    float4 x1 = *(const float4*)(bp + k0 + 4);
    float4 y0 = *(const float4*)(bp + k0 + 32);
    float4 y1 = *(const float4*)(bp + k0 + 36);
    for (int ks = k0; ks < k0 + klen; ks += 32) {
        float xs[8] = {x0.x, x0.y, x0.z, x0.w, x1.x, x1.y, x1.z, x1.w};
        x0 = y0; x1 = y1;
        if (ks + 64 < k0 + klen) {
            y0 = *(const float4*)(bp + ks + 64);
            y1 = *(const float4*)(bp + ks + 68);
        }
        bf16x8 bh, bl;
        #pragma unroll
        for (int q = 0; q < 8; ++q) {
            short h = f2bf(xs[q]);
            bh[q] = h;
            bl[q] = f2bf(xs[q] - bf2f(h));
        }
        #pragma unroll
        for (int j = 0; j < 8; ++j) {
            bf16x8 kh = *(const bf16x8*)(aph + (size_t)16 * K * j + ks);
            bf16x8 kl = *(const bf16x8*)(apl + (size_t)16 * K * j + ks);
            acc[j] = __builtin_amdgcn_mfma_f32_16x16x32_bf16(bh, kh, acc[j], 0, 0, 0);
            acc[j] = __builtin_amdgcn_mfma_f32_16x16x32_bf16(bl, kh, acc[j], 0, 0, 0);
            acc[j] = __builtin_amdgcn_mfma_f32_16x16x32_bf16(bh, kl, acc[j], 0, 0, 0);
        }
    }
    const int crow0 = ntile + (lane >> 4) * 4;
    const int ccol = lane & 15;
    #pragma unroll
    for (int j = 0; j < 8; ++j) {
        float4 o = {acc[j][0], acc[j][1], acc[j][2], acc[j][3]};
        *(float4*)(Cb + (size_t)(16 * j + ccol) * N + crow0) = o;
    }
}

// ------------- reduce S K-split partials -> out -------------
__global__ __launch_bounds__(256) void reduceS_kernel(
    const float* __restrict__ part, float* __restrict__ out, int elems4, int S)
{
    int i = blockIdx.x * blockDim.x + threadIdx.x;
    if (i < elems4) {
        float4 s = {0.f, 0.f, 0.f, 0.f};
        for (int r = 0; r < S; ++r) {
            float4 v = *(const float4*)(part + (size_t)r * elems4 * 4 + (size_t)i * 4);
            s.x += v.x; s.y += v.y; s.z += v.z; s.w += v.w;
        }
        *(float4*)(out + (size_t)i * 4) = s;
    }
}

// --- select: exact top-32 idx + top-64 cand + near-boundary flag, single pass ---
// key = (sortable_float_bits << 32) | ~idx  (value desc, index asc)
#define FNT 512
__global__ __launch_bounds__(FNT) void select_kernel(
    const float* __restrict__ scores, int n, int* __restrict__ idx_out,
    int* __restrict__ cand_out, int* __restrict__ flags, float eps)
{
    __shared__ unsigned long long lkey[8 * FNT];
    __shared__ unsigned long long wkey[FNT / 64];
    const int t = threadIdx.x;
    const int b = blockIdx.x;
    const float* row = scores + (size_t)b * n;

    unsigned long long kl[8];
    #pragma unroll
    for (int i = 0; i < 8; ++i) kl[i] = 0ull;

    const int nvec = n >> 2;
    for (int base = t; base < nvec; base += FNT) {
        float4 x4 = *(const float4*)(row + base * 4);
        float xs[4] = {x4.x, x4.y, x4.z, x4.w};
        #pragma unroll
        for (int q = 0; q < 4; ++q) {
            unsigned fb = __float_as_uint(xs[q]);
            unsigned s = (fb & 0x80000000u) ? ~fb : (fb | 0x80000000u);
            unsigned idx = (unsigned)(base * 4 + q);
            unsigned long long key = ((unsigned long long)s << 32) | (unsigned long long)(~idx);
            if (key > kl[7]) {
                unsigned long long c = key;
                #pragma unroll
                for (int i = 0; i < 8; ++i) {
                    unsigned long long old = kl[i];
                    bool gt = c > old;
                    kl[i] = gt ? c : old;
                    c = gt ? old : c;
                }
            }
        }
    }
    #pragma unroll
    for (int i = 0; i < 8; ++i) lkey[i * FNT + t] = kl[i];
    __syncthreads();

    int h = 0;
    float v31 = 0.f, v32 = 0.f;
    for (int sel = 0; sel < 64; ++sel) {
        unsigned long long cnd = (h < 8) ? lkey[h * FNT + t] : 0ull;
        unsigned long long bk = cnd;
        #pragma unroll
        for (int s2 = 1; s2 < 64; s2 <<= 1) {
            unsigned long long o = __shfl_xor(bk, s2);
            if (o > bk) bk = o;
        }
        if ((t & 63) == 0) wkey[t >> 6] = bk;
        __syncthreads();
        unsigned long long g = wkey[0];
        #pragma unroll
        for (int ww = 1; ww < FNT / 64; ++ww) {
            unsigned long long o = wkey[ww];
            if (o > g) g = o;
        }
        if (t == 0) {
            cand_out[b * 64 + sel] = (int)(~(unsigned)g);
            if (sel < TOPK) idx_out[b * TOPK + sel] = (int)(~(unsigned)g);
            unsigned hi = (unsigned)(g >> 32);
            float val = (hi & 0x80000000u) ? __uint_as_float(hi ^ 0x80000000u)
                                           : __uint_as_float(~hi);
            if (sel == 31) v31 = val;
            if (sel == 32) v32 = val;
        }
        if (cnd == g) h++;
        __syncthreads();
    }
    if (t == 0) flags[b] = (v31 - v32 < eps) ? 1 : 0;
}

// ------- exact fp32 rescore of candidate slice (flagged rows only) -------
__global__ __launch_bounds__(256) void rescore_part_kernel(
    const float* __restrict__ Arows, const float* __restrict__ Brows,
    const int* __restrict__ cand, int K, unsigned long long* __restrict__ keybuf,
    const int* __restrict__ flags)
{
    __shared__ float arow[4096];
    const int t = threadIdx.x;
    const int b = blockIdx.x;
    if (!flags[b]) return;
    const int s = blockIdx.y;
    const int cper = 64 / gridDim.y;
    for (int i = t; i < (K >> 2); i += 256)
        ((float4*)arow)[i] = ((const float4*)(Arows + (size_t)b * K))[i];
    __syncthreads();
    const int w = t >> 6, lane = t & 63;
    for (int c = s * cper + w; c < s * cper + cper; c += 4) {
        int r = cand[b * 64 + c];
        const float4* bp = (const float4*)(Brows + (size_t)r * K);
        float sum = 0.f;
        for (int q = lane; q < (K >> 2); q += 64) {
            float4 bv = bp[q];
            float4 av = ((float4*)arow)[q];
            sum = fmaf(av.x, bv.x, fmaf(av.y, bv.y, fmaf(av.z, bv.z, fmaf(av.w, bv.w, sum))));
        }
        #pragma unroll
        for (int sh = 1; sh < 64; sh <<= 1) sum += __shfl_xor(sum, sh);
        if (lane == 0) {
            unsigned fb = __float_as_uint(sum);
            unsigned ss = (fb & 0x80000000u) ? ~fb : (fb | 0x80000000u);
            keybuf[b * 64 + c] = ((unsigned long long)ss << 32) | (unsigned long long)(~(unsigned)r);
        }
    }
}

// ------- 1-wave exact top-32 from 64 packed keys (flagged rows only) -------
__global__ __launch_bounds__(64) void top32_keys_kernel(
    const unsigned long long* __restrict__ keybuf, int* __restrict__ idx_out,
    const int* __restrict__ flags)
{
    const int b = blockIdx.x, t = threadIdx.x;
    if (!flags[b]) return;
    unsigned long long key = keybuf[b * 64 + t];
    int* out = idx_out + b * TOPK;
    for (int sel = 0; sel < TOPK; ++sel) {
        unsigned long long g = key;
        #pragma unroll
        for (int sh = 1; sh < 64; sh <<= 1) {
            unsigned long long o = __shfl_xor(g, sh);
            if (o > g) g = o;
        }
        if (t == 0) out[sel] = (int)(~(unsigned)g);
        if (key == g) key = 0ull;
    }
}

// ---- gather-sum 32 rows of clique_encoder (column half) + partial sumsq ----
__global__ __launch_bounds__(256) void gather_sum_kernel(
    const float* __restrict__ enc, const int* __restrict__ idx,
    float* __restrict__ p_raw, float* __restrict__ ssp)
{
    __shared__ int rows[TOPK];
    __shared__ float red[256];
    const int t = threadIdx.x;
    const int half = blockIdx.x;
    const int b = blockIdx.y;
    if (t < TOPK) rows[t] = idx[b * TOPK + t];
    __syncthreads();
    const int base = half * 2048 + t * 8;
    float4 a0 = {}, a1 = {};
    #pragma unroll 4
    for (int r = 0; r < TOPK; ++r) {
        const float* src = enc + (size_t)rows[r] * D + base;
        float4 v0 = *(const float4*)(src);
        float4 v1 = *(const float4*)(src + 4);
        a0.x += v0.x; a0.y += v0.y; a0.z += v0.z; a0.w += v0.w;
        a1.x += v1.x; a1.y += v1.y; a1.z += v1.z; a1.w += v1.w;
    }
    const float sc = 0.17677669529663687f; // 1/sqrt(32)
    a0.x *= sc; a0.y *= sc; a0.z *= sc; a0.w *= sc;
    a1.x *= sc; a1.y *= sc; a1.z *= sc; a1.w *= sc;
    float ss = a0.x*a0.x + a0.y*a0.y + a0.z*a0.z + a0.w*a0.w
             + a1.x*a1.x + a1.y*a1.y + a1.z*a1.z + a1.w*a1.w;
    red[t] = ss;
    __syncthreads();
    for (int s = 128; s > 0; s >>= 1) {
        if (t < s) red[t] += red[t + s];
        __syncthreads();
    }
    if (t == 0) ssp[b * 2 + half] = red[0];
    float* dst = p_raw + (size_t)b * D + base;
    *(float4*)dst = a0;
    *(float4*)(dst + 4) = a1;
}

// ---- finish normalize: p (fp32) + hi/lo bf16 split ----
__global__ __launch_bounds__(256) void normalize_kernel(
    const float* __restrict__ p_raw, const float* __restrict__ ssp,
    float* __restrict__ p, short* __restrict__ p_hi, short* __restrict__ p_lo)
{
    const int b = blockIdx.x, t = threadIdx.x;
    const float rinv = 1.0f / fmaxf(sqrtf(ssp[b * 2] + ssp[b * 2 + 1]), 1e-12f);
    for (int i = t; i < (D >> 2); i += 256) {
        float4 v = ((const float4*)(p_raw + (size_t)b * D))[i];
        float4 o = {v.x * rinv, v.y * rinv, v.z * rinv, v.w * rinv};
        ((float4*)(p + (size_t)b * D))[i] = o;
        short4 oh = {f2bf(o.x), f2bf(o.y), f2bf(o.z), f2bf(o.w)};
        short4 ol = {f2bf(o.x - bf2f(oh.x)), f2bf(o.y - bf2f(oh.y)),
                     f2bf(o.z - bf2f(oh.z)), f2bf(o.w - bf2f(oh.w))};
        ((short4*)(p_hi + (size_t)b * D))[i] = oh;
        ((short4*)(p_lo + (size_t)b * D))[i] = ol;
    }
}

// -------- gather 32 rows of assoc_mem_value, sum -> out --------
// grid.x = b (fast dim), grid.y = column chunk; dynamic LDS throttles occupancy
// so co-resident blocks share a chunk's distinct-row footprint in L2/L3.
__global__ __launch_bounds__(256) void gather_out_kernel(
    const float* __restrict__ mem, const int* __restrict__ idx, float* __restrict__ out)
{
    extern __shared__ float throttle[];
    __shared__ int rows[TOPK];
    const int t = threadIdx.x;
    const int b = blockIdx.x;
    const int chunk = blockIdx.y;
    if (t < TOPK) rows[t] = idx[b * TOPK + t];
    __syncthreads();
    const int off = chunk * 2048 + t * 8;
    float4 a0 = {}, a1 = {};
    #pragma unroll 4
    for (int r = 0; r < TOPK; ++r) {
        const float* src = mem + (size_t)rows[r] * NVAL + off;
        float4 v0 = *(const float4*)(src);
        float4 v1 = *(const float4*)(src + 4);
        a0.x += v0.x; a0.y += v0.y; a0.z += v0.z; a0.w += v0.w;
        a1.x += v1.x; a1.y += v1.y; a1.z += v1.z; a1.w += v1.w;
    }
    if (rows[0] < 0) { throttle[t] = a0.x; out[0] = throttle[t + 1]; } // keep LDS alloc
    float* dst = out + (size_t)b * NVAL + off;
    *(float4*)dst = a0;
    *(float4*)(dst + 4) = a1;
}

extern "C" void kernel_launch(void* const* d_in, const int* in_sizes, int n_in,
                              void* d_out, int out_size, void* d_ws, size_t ws_size,
                              hipStream_t stream) {
    const float* keys            = (const float*)d_in[0];
    const float* value_proj      = (const float*)d_in[1];
    const float* clique_encoder  = (const float*)d_in[2];
    const float* assoc_proj      = (const float*)d_in[3];
    const float* assoc_mem_value = (const float*)d_in[4];
    float* out = (float*)d_out;

    char* ws = (char*)d_ws;
    short* keys_hi = (short*)(ws);                          // 256 KB
    short* keys_lo = (short*)(ws + 262144);                 // 256 KB
    float* s1a     = (float*)(ws + 524288);                 // 16 MB
    float* p_raw   = (float*)(ws + 17301504);               // 2 MB
    float* p       = (float*)(ws + 19398656);               // 2 MB
    short* p_hi    = (short*)(ws + 21495808);               // 1 MB
    short* p_lo    = (short*)(ws + 22544384);               // 1 MB
    float* part2   = (float*)(ws + 23592960);               // 16 MB (8 splits)
    float* s2a     = (float*)(ws + 40370176);               // 2 MB
    int*   cand1   = (int*)  (ws + 42467328);               // 32 KB
    int*   cand2   = (int*)  (ws + 42500096);               // 32 KB
    int*   idx1    = (int*)  (ws + 42532864);               // 16 KB
    int*   idx2    = (int*)  (ws + 42549248);               // 16 KB
    unsigned long long* keyb1 = (unsigned long long*)(ws + 42565632);  // 64 KB
    unsigned long long* keyb2 = (unsigned long long*)(ws + 42631168);  // 64 KB
    float* ssp     = (float*)(ws + 42696704);               // 1 KB
    int*   flags1  = (int*)  (ws + 42697728);               // 512 B
    int*   flags2  = (int*)  (ws + 42698240);               // 512 B

    // 1) keys -> bf16 hi/lo
    cvt_split_kernel<<<128, 256, 0, stream>>>(keys, keys_hi, keys_lo, 32768);
    // 2) scores1 = keys @ value_proj^T via split-bf16 (err ~5e-6), full K
    gemm_split_kernel<<<dim3(512, 1), 256, 0, stream>>>(keys_hi, keys_lo, value_proj, s1a, 1024, NVAL, 1024);
    // 3) exact top-32 + cand64 + flag (eps = 40 sigma of split error)
    select_kernel<<<128, FNT, 0, stream>>>(s1a, NVAL, idx1, cand1, flags1, 2e-4f);
    // 4+5) flagged-only fp32 rescore + reselect (expected ~3/128 rows)
    rescore_part_kernel<<<dim3(128, 4), 256, 0, stream>>>(keys, value_proj, cand1, 1024, keyb1, flags1);
    top32_keys_kernel<<<128, 64, 0, stream>>>(keyb1, idx1, flags1);
    // 6) gather-sum clique_encoder rows (2-way column split)
    gather_sum_kernel<<<dim3(2, 128), 256, 0, stream>>>(clique_encoder, idx1, p_raw, ssp);
    // 7) normalize -> p, p_hi, p_lo
    normalize_kernel<<<128, 256, 0, stream>>>(p_raw, ssp, p, p_hi, p_lo);
    // 8) scores2 via split-bf16, 8-way K-split (2 blocks/CU)
    gemm_split_kernel<<<dim3(64, 8), 256, 0, stream>>>(p_hi, p_lo, assoc_proj, part2, 4096, D, 512);
    // 9) reduce partials
    reduceS_kernel<<<512, 256, 0, stream>>>(part2, s2a, 131072, 8);
    // 10) exact top-32 + cand64 + flag (eps = 100 sigma)
    select_kernel<<<128, FNT, 0, stream>>>(s2a, D, idx2, cand2, flags2, 1e-5f);
    // 11+12) flagged-only fp32 rescore + reselect (expected ~7/128 rows)
    rescore_part_kernel<<<dim3(128, 4), 256, 0, stream>>>(p, assoc_proj, cand2, 4096, keyb2, flags2);
    top32_keys_kernel<<<128, 64, 0, stream>>>(keyb2, idx2, flags2);
    // 13) out = sum(assoc_mem_value[idx2]) with L3-friendly ordering
    gather_out_kernel<<<dim3(128, 16), 256, 40960, stream>>>(assoc_mem_value, idx2, out);
}

// Round 8
// 405.056 us; speedup vs baseline: 1.2019x; 1.2019x over previous
//
#include <hip/hip_runtime.h>
#include <math.h>

#define TOPK 32
#define NVAL 32768
#define D 4096

typedef __attribute__((ext_vector_type(8))) short bf16x8;
typedef __attribute__((ext_vector_type(4))) float f32x4;

__device__ inline short f2bf(float x) {
    union { float f; unsigned u; } v; v.f = x;
    unsigned r = v.u + 0x7fffu + ((v.u >> 16) & 1u);  // RNE
    return (short)(r >> 16);
}

// ---------------- fp32 -> bf16 streaming convert ----------------
__global__ __launch_bounds__(256) void cvt_bf16_kernel(
    const float* __restrict__ in, short* __restrict__ out, int n4)
{
    int i = blockIdx.x * 256 + threadIdx.x;
    if (i < n4) {
        float4 v = ((const float4*)in)[i];
        short4 o = {f2bf(v.x), f2bf(v.y), f2bf(v.z), f2bf(v.w)};
        ((short4*)out)[i] = o;
    }
}

// ------- stage-1 approx GEMM: C[128 x N] = A(bf16) @ bf16(B)^T, full K, 3-deep prefetch -------
__global__ __launch_bounds__(256) void gemm_bf16_kernel(
    const short* __restrict__ Abf, const float* __restrict__ B,
    float* __restrict__ C, int K, int N)
{
    const int t = threadIdx.x;
    const int lane = t & 63;
    const int w = t >> 6;
    const int ntile = blockIdx.x * 64 + w * 16;

    const int kfrag = (lane >> 4) * 8;
    const float* bp = B + (size_t)(ntile + (lane & 15)) * K + kfrag;
    const short* ap = Abf + (size_t)(lane & 15) * K + kfrag;

    f32x4 acc[8];
    #pragma unroll
    for (int j = 0; j < 8; ++j) acc[j] = (f32x4){0.f, 0.f, 0.f, 0.f};

    float4 x0 = *(const float4*)(bp);
    float4 x1 = *(const float4*)(bp + 4);
    float4 y0 = *(const float4*)(bp + 32);
    float4 y1 = *(const float4*)(bp + 36);
    float4 z0 = *(const float4*)(bp + 64);
    float4 z1 = *(const float4*)(bp + 68);
    for (int ks = 0; ks < K; ks += 32) {
        bf16x8 af;
        af[0] = f2bf(x0.x); af[1] = f2bf(x0.y); af[2] = f2bf(x0.z); af[3] = f2bf(x0.w);
        af[4] = f2bf(x1.x); af[5] = f2bf(x1.y); af[6] = f2bf(x1.z); af[7] = f2bf(x1.w);
        x0 = y0; x1 = y1; y0 = z0; y1 = z1;
        if (ks + 96 < K) {
            z0 = *(const float4*)(bp + ks + 96);
            z1 = *(const float4*)(bp + ks + 100);
        }
        #pragma unroll
        for (int j = 0; j < 8; ++j) {
            bf16x8 kf = *(const bf16x8*)(ap + (size_t)16 * K * j + ks);
            acc[j] = __builtin_amdgcn_mfma_f32_16x16x32_bf16(af, kf, acc[j], 0, 0, 0);
        }
    }
    const int crow0 = ntile + (lane >> 4) * 4;
    const int ccol = lane & 15;
    #pragma unroll
    for (int j = 0; j < 8; ++j) {
        float4 o = {acc[j][0], acc[j][1], acc[j][2], acc[j][3]};
        *(float4*)(C + (size_t)(16 * j + ccol) * N + crow0) = o;
    }
}

// ------- stage-2 approx GEMM: K-split (grid.y), 2-deep prefetch -------
__global__ __launch_bounds__(256) void gemm_bf16_k_kernel(
    const short* __restrict__ Abf, const float* __restrict__ B,
    float* __restrict__ C, int K, int N, int klen)
{
    const int t = threadIdx.x;
    const int lane = t & 63;
    const int w = t >> 6;
    const int ntile = blockIdx.x * 64 + w * 16;
    const int k0 = blockIdx.y * klen;
    float* Cb = C + (size_t)blockIdx.y * 128 * N;

    const int kfrag = (lane >> 4) * 8;
    const float* bp = B + (size_t)(ntile + (lane & 15)) * K + kfrag;
    const short* ap = Abf + (size_t)(lane & 15) * K + kfrag;

    f32x4 acc[8];
    #pragma unroll
    for (int j = 0; j < 8; ++j) acc[j] = (f32x4){0.f, 0.f, 0.f, 0.f};

    float4 x0 = *(const float4*)(bp + k0);
    float4 x1 = *(const float4*)(bp + k0 + 4);
    float4 y0 = *(const float4*)(bp + k0 + 32);
    float4 y1 = *(const float4*)(bp + k0 + 36);
    for (int ks = k0; ks < k0 + klen; ks += 32) {
        bf16x8 af;
        af[0] = f2bf(x0.x); af[1] = f2bf(x0.y); af[2] = f2bf(x0.z); af[3] = f2bf(x0.w);
        af[4] = f2bf(x1.x); af[5] = f2bf(x1.y); af[6] = f2bf(x1.z); af[7] = f2bf(x1.w);
        x0 = y0; x1 = y1;
        if (ks + 64 < k0 + klen) {
            y0 = *(const float4*)(bp + ks + 64);
            y1 = *(const float4*)(bp + ks + 68);
        }
        #pragma unroll
        for (int j = 0; j < 8; ++j) {
            bf16x8 kf = *(const bf16x8*)(ap + (size_t)16 * K * j + ks);
            acc[j] = __builtin_amdgcn_mfma_f32_16x16x32_bf16(af, kf, acc[j], 0, 0, 0);
        }
    }
    const int crow0 = ntile + (lane >> 4) * 4;
    const int ccol = lane & 15;
    #pragma unroll
    for (int j = 0; j < 8; ++j) {
        float4 o = {acc[j][0], acc[j][1], acc[j][2], acc[j][3]};
        *(float4*)(Cb + (size_t)(16 * j + ccol) * N + crow0) = o;
    }
}

// ------------- reduce S K-split partials -> out -------------
__global__ __launch_bounds__(256) void reduceS_kernel(
    const float* __restrict__ part, float* __restrict__ out, int elems4, int S)
{
    int i = blockIdx.x * blockDim.x + threadIdx.x;
    if (i < elems4) {
        float4 s = {0.f, 0.f, 0.f, 0.f};
        for (int r = 0; r < S; ++r) {
            float4 v = *(const float4*)(part + (size_t)r * elems4 * 4 + (size_t)i * 4);
            s.x += v.x; s.y += v.y; s.z += v.z; s.w += v.w;
        }
        *(float4*)(out + (size_t)i * 4) = s;
    }
}

// ------------- top-64 candidate filter per row -------------
// key = (sortable_float_bits << 32) | ~idx  (value desc, index asc)
#define FNT 512
__global__ __launch_bounds__(FNT) void filter64_kernel(
    const float* __restrict__ scores, int n, int* __restrict__ cand_out)
{
    __shared__ unsigned long long lkey[8 * FNT];
    __shared__ unsigned long long wkey[FNT / 64];
    const int t = threadIdx.x;
    const float* row = scores + (size_t)blockIdx.x * n;

    unsigned long long kl[8];
    #pragma unroll
    for (int i = 0; i < 8; ++i) kl[i] = 0ull;

    const int nvec = n >> 2;
    for (int base = t; base < nvec; base += FNT) {
        float4 x4 = *(const float4*)(row + base * 4);
        float xs[4] = {x4.x, x4.y, x4.z, x4.w};
        #pragma unroll
        for (int q = 0; q < 4; ++q) {
            unsigned fb = __float_as_uint(xs[q]);
            unsigned s = (fb & 0x80000000u) ? ~fb : (fb | 0x80000000u);
            unsigned idx = (unsigned)(base * 4 + q);
            unsigned long long key = ((unsigned long long)s << 32) | (unsigned long long)(~idx);
            if (key > kl[7]) {
                unsigned long long c = key;
                #pragma unroll
                for (int i = 0; i < 8; ++i) {
                    unsigned long long old = kl[i];
                    bool gt = c > old;
                    kl[i] = gt ? c : old;
                    c = gt ? old : c;
                }
            }
        }
    }
    #pragma unroll
    for (int i = 0; i < 8; ++i) lkey[i * FNT + t] = kl[i];
    __syncthreads();

    int h = 0;
    int* out = cand_out + blockIdx.x * 64;
    for (int sel = 0; sel < 64; ++sel) {
        unsigned long long cnd = (h < 8) ? lkey[h * FNT + t] : 0ull;
        unsigned long long b = cnd;
        #pragma unroll
        for (int s2 = 1; s2 < 64; s2 <<= 1) {
            unsigned long long o = __shfl_xor(b, s2);
            if (o > b) b = o;
        }
        if ((t & 63) == 0) wkey[t >> 6] = b;
        __syncthreads();
        unsigned long long g = wkey[0];
        #pragma unroll
        for (int ww = 1; ww < FNT / 64; ++ww) {
            unsigned long long o = wkey[ww];
            if (o > g) g = o;
        }
        if (t == 0) out[sel] = (int)(~(unsigned)g);
        if (cnd == g) h++;
        __syncthreads();
    }
}

// ------- exact fp32 rescore of candidate slice -> packed keys -------
__global__ __launch_bounds__(256) void rescore_part_kernel(
    const float* __restrict__ Arows, const float* __restrict__ Brows,
    const int* __restrict__ cand, int K, unsigned long long* __restrict__ keybuf)
{
    __shared__ float arow[4096];
    const int t = threadIdx.x;
    const int b = blockIdx.x;
    const int s = blockIdx.y;
    const int cper = 64 / gridDim.y;
    for (int i = t; i < (K >> 2); i += 256)
        ((float4*)arow)[i] = ((const float4*)(Arows + (size_t)b * K))[i];
    __syncthreads();
    const int w = t >> 6, lane = t & 63;
    for (int c = s * cper + w; c < s * cper + cper; c += 4) {
        int r = cand[b * 64 + c];
        const float4* bp = (const float4*)(Brows + (size_t)r * K);
        float sum = 0.f;
        for (int q = lane; q < (K >> 2); q += 64) {
            float4 bv = bp[q];
            float4 av = ((float4*)arow)[q];
            sum = fmaf(av.x, bv.x, fmaf(av.y, bv.y, fmaf(av.z, bv.z, fmaf(av.w, bv.w, sum))));
        }
        #pragma unroll
        for (int sh = 1; sh < 64; sh <<= 1) sum += __shfl_xor(sum, sh);
        if (lane == 0) {
            unsigned fb = __float_as_uint(sum);
            unsigned ss = (fb & 0x80000000u) ? ~fb : (fb | 0x80000000u);
            keybuf[b * 64 + c] = ((unsigned long long)ss << 32) | (unsigned long long)(~(unsigned)r);
        }
    }
}

// ------- 1-wave exact top-32 from 64 packed keys -------
__global__ __launch_bounds__(64) void top32_keys_kernel(
    const unsigned long long* __restrict__ keybuf, int* __restrict__ idx_out)
{
    const int b = blockIdx.x, t = threadIdx.x;
    unsigned long long key = keybuf[b * 64 + t];
    int* out = idx_out + b * TOPK;
    for (int sel = 0; sel < TOPK; ++sel) {
        unsigned long long g = key;
        #pragma unroll
        for (int sh = 1; sh < 64; sh <<= 1) {
            unsigned long long o = __shfl_xor(g, sh);
            if (o > g) g = o;
        }
        if (t == 0) out[sel] = (int)(~(unsigned)g);
        if (key == g) key = 0ull;
    }
}

// ---- gather-sum 32 rows of clique_encoder (column quarter) + partial sumsq ----
__global__ __launch_bounds__(256) void gather_sum_kernel(
    const float* __restrict__ enc, const int* __restrict__ idx,
    float* __restrict__ p_raw, float* __restrict__ ssp)
{
    __shared__ int rows[TOPK];
    __shared__ float red[256];
    const int t = threadIdx.x;
    const int quarter = blockIdx.x;
    const int b = blockIdx.y;
    if (t < TOPK) rows[t] = idx[b * TOPK + t];
    __syncthreads();
    const int base = quarter * 1024 + t * 4;
    float4 a0 = {};
    #pragma unroll 4
    for (int r = 0; r < TOPK; ++r) {
        const float4 v0 = *(const float4*)(enc + (size_t)rows[r] * D + base);
        a0.x += v0.x; a0.y += v0.y; a0.z += v0.z; a0.w += v0.w;
    }
    const float sc = 0.17677669529663687f; // 1/sqrt(32)
    a0.x *= sc; a0.y *= sc; a0.z *= sc; a0.w *= sc;
    float ss = a0.x*a0.x + a0.y*a0.y + a0.z*a0.z + a0.w*a0.w;
    red[t] = ss;
    __syncthreads();
    for (int s = 128; s > 0; s >>= 1) {
        if (t < s) red[t] += red[t + s];
        __syncthreads();
    }
    if (t == 0) ssp[b * 4 + quarter] = red[0];
    *(float4*)(p_raw + (size_t)b * D + base) = a0;
}

// ---- finish normalize: p (fp32) + p_bf (bf16) ----
__global__ __launch_bounds__(256) void normalize_kernel(
    const float* __restrict__ p_raw, const float* __restrict__ ssp,
    float* __restrict__ p, short* __restrict__ p_bf)
{
    const int b = blockIdx.x, t = threadIdx.x;
    const float rinv = 1.0f / fmaxf(sqrtf(ssp[b*4] + ssp[b*4+1] + ssp[b*4+2] + ssp[b*4+3]), 1e-12f);
    for (int i = t; i < (D >> 2); i += 256) {
        float4 v = ((const float4*)(p_raw + (size_t)b * D))[i];
        float4 o = {v.x * rinv, v.y * rinv, v.z * rinv, v.w * rinv};
        ((float4*)(p + (size_t)b * D))[i] = o;
        short4 ob = {f2bf(o.x), f2bf(o.y), f2bf(o.z), f2bf(o.w)};
        ((short4*)(p_bf + (size_t)b * D))[i] = ob;
    }
}

// -------- gather 32 rows of assoc_mem_value, sum -> out --------
// grid.x = b (fast dim), grid.y = column chunk; dynamic LDS throttles occupancy
// so co-resident blocks share a chunk's distinct-row footprint in L2/L3.
__global__ __launch_bounds__(256) void gather_out_kernel(
    const float* __restrict__ mem, const int* __restrict__ idx, float* __restrict__ out)
{
    extern __shared__ float throttle[];
    __shared__ int rows[TOPK];
    const int t = threadIdx.x;
    const int b = blockIdx.x;
    const int chunk = blockIdx.y;
    if (t < TOPK) rows[t] = idx[b * TOPK + t];
    __syncthreads();
    const int off = chunk * 2048 + t * 8;
    float4 a0 = {}, a1 = {};
    #pragma unroll 4
    for (int r = 0; r < TOPK; ++r) {
        const float* src = mem + (size_t)rows[r] * NVAL + off;
        float4 v0 = *(const float4*)(src);
        float4 v1 = *(const float4*)(src + 4);
        a0.x += v0.x; a0.y += v0.y; a0.z += v0.z; a0.w += v0.w;
        a1.x += v1.x; a1.y += v1.y; a1.z += v1.z; a1.w += v1.w;
    }
    if (rows[0] < 0) { throttle[t] = a0.x; out[0] = throttle[t + 1]; } // keep LDS alloc
    float* dst = out + (size_t)b * NVAL + off;
    *(float4*)dst = a0;
    *(float4*)(dst + 4) = a1;
}

extern "C" void kernel_launch(void* const* d_in, const int* in_sizes, int n_in,
                              void* d_out, int out_size, void* d_ws, size_t ws_size,
                              hipStream_t stream) {
    const float* keys            = (const float*)d_in[0];
    const float* value_proj      = (const float*)d_in[1];
    const float* clique_encoder  = (const float*)d_in[2];
    const float* assoc_proj      = (const float*)d_in[3];
    const float* assoc_mem_value = (const float*)d_in[4];
    float* out = (float*)d_out;

    char* ws = (char*)d_ws;
    short* keysbf = (short*)(ws);                           // 256 KB
    float* s1a    = (float*)(ws + 262144);                  // 16 MB
    float* p_raw  = (float*)(ws + 17039360);                // 2 MB
    float* p      = (float*)(ws + 19136512);                // 2 MB
    short* p_bf   = (short*)(ws + 21233664);                // 1 MB
    float* part2  = (float*)(ws + 22282240);                // 16 MB (8 splits)
    float* s2a    = (float*)(ws + 39059456);                // 2 MB
    int*   cand1  = (int*)  (ws + 41156608);                // 32 KB
    int*   cand2  = (int*)  (ws + 41189376);                // 32 KB
    int*   idx1   = (int*)  (ws + 41222144);                // 16 KB
    int*   idx2   = (int*)  (ws + 41238528);                // 16 KB
    unsigned long long* keyb1 = (unsigned long long*)(ws + 41254912);  // 64 KB
    unsigned long long* keyb2 = (unsigned long long*)(ws + 41320448);  // 64 KB
    float* ssp    = (float*)(ws + 41385984);                // 2 KB

    // 1) keys -> bf16
    cvt_bf16_kernel<<<128, 256, 0, stream>>>(keys, keysbf, 32768);
    // 2) approx scores1 = keysbf @ bf16(value_proj)^T
    gemm_bf16_kernel<<<dim3(512), 256, 0, stream>>>(keysbf, value_proj, s1a, 1024, NVAL);
    // 3) top-64 candidates
    filter64_kernel<<<128, FNT, 0, stream>>>(s1a, NVAL, cand1);
    // 4) exact fp32 rescore (8-way split) -> keys
    rescore_part_kernel<<<dim3(128, 8), 256, 0, stream>>>(keys, value_proj, cand1, 1024, keyb1);
    // 5) exact top-32 idx1
    top32_keys_kernel<<<128, 64, 0, stream>>>(keyb1, idx1);
    // 6) gather-sum clique_encoder rows (4-way column split)
    gather_sum_kernel<<<dim3(4, 128), 256, 0, stream>>>(clique_encoder, idx1, p_raw, ssp);
    // 7) normalize -> p, p_bf
    normalize_kernel<<<128, 256, 0, stream>>>(p_raw, ssp, p, p_bf);
    // 8) approx scores2 = p_bf @ bf16(assoc_proj)^T, 8-way K-split (2 blocks/CU)
    gemm_bf16_k_kernel<<<dim3(64, 8), 256, 0, stream>>>(p_bf, assoc_proj, part2, 4096, D, 512);
    // 9) reduce partials
    reduceS_kernel<<<512, 256, 0, stream>>>(part2, s2a, 131072, 8);
    // 10) top-64 candidates (n=4096)
    filter64_kernel<<<128, FNT, 0, stream>>>(s2a, D, cand2);
    // 11) exact fp32 rescore (8-way split) -> keys
    rescore_part_kernel<<<dim3(128, 8), 256, 0, stream>>>(p, assoc_proj, cand2, 4096, keyb2);
    // 12) exact top-32 idx2
    top32_keys_kernel<<<128, 64, 0, stream>>>(keyb2, idx2);
    // 13) out = sum(assoc_mem_value[idx2]) with L3-friendly ordering
    gather_out_kernel<<<dim3(128, 16), 256, 40960, stream>>>(assoc_mem_value, idx2, out);
}